// Round 3
// baseline (336.210 us; speedup 1.0000x reference)
//
#include <hip/hip_runtime.h>

// NanoMolmo visual-token merge.
// merged[b, j] = visual[b, j-ip]          if ip <= j < ip+576
//             = 0                         if j == 0 and ip != 0   (XLA scatter
//                                           duplicate-index quirk: image pos's
//                                           dummy write of buf[0]=0 lands last)
//             = table[ids[b, j]]          if j < ip
//             = table[ids[b, j-575]]      if j >= ip+576
// position_ids[b, j] = j  -- written as FLOAT: harness reads whole d_out as f32.

#define IMAGE_TOKEN_ID 31999
#define B_ 4
#define L_ 1024
#define D_ 2048
#define NUM_VIS_ 576
#define NEW_LEN_ (L_ - 1 + NUM_VIS_)   // 1599

__global__ void find_img_pos_kernel(const int* __restrict__ ids,
                                    int* __restrict__ pos) {
    int b = blockIdx.x;
    for (int i = threadIdx.x; i < L_; i += blockDim.x) {
        if (ids[b * L_ + i] == IMAGE_TOKEN_ID) pos[b] = i;   // exactly one per row
    }
}

__global__ void merge_kernel(const int* __restrict__ ids,
                             const float4* __restrict__ vis,
                             const float4* __restrict__ table,
                             const int* __restrict__ imgpos,
                             float4* __restrict__ out,
                             float* __restrict__ pos_out) {
    const int D4 = D_ / 4;               // 512 float4 per row
    int row = blockIdx.x;                // 0 .. B*NEW_LEN-1
    int b = row / NEW_LEN_;
    int j = row - b * NEW_LEN_;
    int ip = imgpos[b];

    if (threadIdx.x == 0) pos_out[row] = (float)j;   // f32, not int bits

    float4* dst = out + (size_t)row * D4;

    if (j >= ip && j < ip + NUM_VIS_) {
        // visual block
        const float4* src = vis + ((size_t)b * NUM_VIS_ + (j - ip)) * D4;
        for (int t = threadIdx.x; t < D4; t += blockDim.x) dst[t] = src[t];
    } else if (j == 0 && ip != 0) {
        // contested slot 0: image-position dummy write (0.0) lands last
        float4 z = make_float4(0.f, 0.f, 0.f, 0.f);
        for (int t = threadIdx.x; t < D4; t += blockDim.x) dst[t] = z;
    } else {
        int i = (j < ip) ? j : j - (NUM_VIS_ - 1);
        int tok = ids[b * L_ + i];
        const float4* src = table + (size_t)tok * D4;
        for (int t = threadIdx.x; t < D4; t += blockDim.x) dst[t] = src[t];
    }
}

extern "C" void kernel_launch(void* const* d_in, const int* in_sizes, int n_in,
                              void* d_out, int out_size, void* d_ws, size_t ws_size,
                              hipStream_t stream) {
    const int*   ids   = (const int*)d_in[0];
    const float* vis   = (const float*)d_in[1];
    const float* table = (const float*)d_in[2];

    float* out_merged = (float*)d_out;
    float* out_pos    = out_merged + (size_t)B_ * NEW_LEN_ * D_;
    int*   imgpos     = (int*)d_ws;      // 4 ints of scratch

    find_img_pos_kernel<<<B_, 256, 0, stream>>>(ids, imgpos);
    merge_kernel<<<B_ * NEW_LEN_, 256, 0, stream>>>(
        ids, (const float4*)vis, (const float4*)table, imgpos,
        (float4*)out_merged, out_pos);
}